// Round 4
// baseline (176.065 us; speedup 1.0000x reference)
//
#include <hip/hip_runtime.h>

#define H 1024
#define NG 65536
#define NSEG 16384

#define FBM 64
#define FBN 256
#define FBK 64
#define NSTEP 64   // 4 n-chunks x 16 k-tiles

typedef __attribute__((ext_vector_type(8))) short bf16x8;
typedef __attribute__((ext_vector_type(4))) float f32x4;

__device__ __forceinline__ unsigned short f2bf(float x) {
    unsigned u = __builtin_bit_cast(unsigned, x);
    unsigned r = (u + 0x7fffu + ((u >> 16) & 1u)) >> 16;
    return (unsigned short)r;
}

__device__ __forceinline__ void gload_lds16(const void* g, void* l) {
    __builtin_amdgcn_global_load_lds(
        (const __attribute__((address_space(1))) void*)g,
        (__attribute__((address_space(3))) void*)l, 16, 0, 0);
}

#define CFENCE() asm volatile("" ::: "memory")

// ---- Setup: convert W to bf16 | segment bounds ----
__global__ void setup_kernel(const float* __restrict__ w, unsigned short* __restrict__ wbf,
                             const int* __restrict__ seg, int* __restrict__ seg_start) {
    int b = blockIdx.x;
    if (b < 1024) {
        int i = (b * 256 + threadIdx.x) * 4;
        float4 v = *(const float4*)(w + i);
        ushort4 o;
        o.x = f2bf(v.x); o.y = f2bf(v.y); o.z = f2bf(v.z); o.w = f2bf(v.w);
        *(ushort4*)(wbf + i) = o;
    } else {
        int g = (b - 1024) * 256 + threadIdx.x;
        if (g > NSEG) return;
        if (g == NSEG) { seg_start[g] = NG; return; }
        int lo = 0, hi = NG;
        while (lo < hi) { int mid = (lo + hi) >> 1; if (seg[mid] < g) lo = mid + 1; else hi = mid; }
        seg_start[g] = lo;
    }
}

// ---- Fused: per-block seg-mean for own 64 rows, then 64x1024 GEMM+GELU+proj ----
__global__ __launch_bounds__(512, 2) void fused_kernel(
    const float* __restrict__ hidden,
    const int* __restrict__ flat_indices,
    const int* __restrict__ seg_start,
    const unsigned short* __restrict__ Wbf,   // dense_w bf16 [H,H], row n contiguous in k
    const float* __restrict__ dense_b,
    const float* __restrict__ proj_w,
    const float* __restrict__ proj_b,
    unsigned short* __restrict__ hbf,         // scratch h bf16 [NSEG, H]
    float* __restrict__ out) {
    __shared__ unsigned short As[2][FBM * FBK];   // 2 x 8 KB
    __shared__ unsigned short Bs[2][FBN * FBK];   // 2 x 32 KB
    const int tid = threadIdx.x;
    const int bid = blockIdx.x;
    const int r0 = bid * FBM;

    // ---- Phase 1: segment mean for rows r0..r0+63 (2 teams x 32 segments) ----
    {
        int team = tid >> 8;       // 0/1 (waves 0-3 vs 4-7)
        int tt = tid & 255;        // k-chunk: floats [4tt, 4tt+4)
        for (int s = 0; s < 32; ++s) {
            int g = r0 + team * 32 + s;
            int st = seg_start[g], en = seg_start[g + 1];
            float4 a = {0.f, 0.f, 0.f, 0.f};
            for (int i = st; i < en; ++i) {
                int row = flat_indices[i];
                float4 v = *((const float4*)(hidden + (size_t)row * H) + tt);
                a.x += v.x; a.y += v.y; a.z += v.z; a.w += v.w;
            }
            float sc = (en > st) ? 1.0f / (float)(en - st) : 0.0f;
            ushort4 o;
            o.x = f2bf(a.x * sc); o.y = f2bf(a.y * sc);
            o.z = f2bf(a.z * sc); o.w = f2bf(a.w * sc);
            *(ushort4*)(hbf + (size_t)g * H + tt * 4) = o;
        }
    }
    __syncthreads();   // h rows of this block visible (L2-local, same CU)

    // ---- Phase 2: GEMM 64 x 1024, n-chunks of 256 inside, K pipelined ----
    const int wid = tid >> 6, lane = tid & 63;
    const int wr = wid >> 2, wc = wid & 3;    // wave tile: 32 rows x 64 cols

    auto STAGE = [&](int buf, int step) {
        int nc = step >> 4, kt = step & 15;
        {   // A tile 64x64: 512 x 16B chunks, 1 per thread
            int c = tid;
            int row = c >> 3;
            int sw = ((c & 7) << 4) ^ ((row & 7) << 4);
            gload_lds16((const char*)hbf + (((size_t)(r0 + row)) << 11) + kt * 128 + sw,
                        (char*)&As[buf][0] + (wid * 64) * 16);
        }
#pragma unroll
        for (int it = 0; it < 4; ++it) {   // B tile 256x64: 2048 chunks
            int c = it * 512 + tid;
            int row = c >> 3;
            int sw = ((c & 7) << 4) ^ ((row & 7) << 4);
            gload_lds16((const char*)Wbf + (((size_t)(nc * FBN + row)) << 11) + kt * 128 + sw,
                        (char*)&Bs[buf][0] + (it * 512 + wid * 64) * 16);
        }
    };

    f32x4 acc[2][4] = {};
    float p[2][4] = {};       // proj partials per (mi, r), accumulated over nc & ni
    float db[4], pw[4];

    STAGE(0, 0);
    for (int s = 0; s < NSTEP; ++s) {
        int kt = s & 15;
        if (kt == 0) {
            int nc = s >> 4;
#pragma unroll
            for (int ni = 0; ni < 4; ++ni) {
                int n = nc * FBN + wc * 64 + ni * 16 + (lane & 15);
                db[ni] = dense_b[n];
                pw[ni] = proj_w[n];
            }
        }
        // Barrier A: everyone done reading the buffer we overwrite next.
        CFENCE();
        __builtin_amdgcn_s_barrier();
        CFENCE();
        if (s + 1 < NSTEP) {
            STAGE((s + 1) & 1, s + 1);
            asm volatile("s_waitcnt vmcnt(5)" ::: "memory");  // tile s landed; s+1 in flight
        } else {
            asm volatile("s_waitcnt vmcnt(0)" ::: "memory");
        }
        __builtin_amdgcn_s_barrier();
        CFENCE();

        const char* Ab = (const char*)&As[s & 1][0];
        const char* Bb = (const char*)&Bs[s & 1][0];
        __builtin_amdgcn_s_setprio(1);
#pragma unroll
        for (int kk = 0; kk < 2; ++kk) {
            bf16x8 af[2], bw[4];
            int kb = kk * 64 + ((lane >> 4) << 4);
#pragma unroll
            for (int ni = 0; ni < 4; ++ni) {
                int row = wc * 64 + ni * 16 + (lane & 15);
                bw[ni] = *(const bf16x8*)(Bb + row * 128 + (kb ^ ((row & 7) << 4)));
            }
#pragma unroll
            for (int mi = 0; mi < 2; ++mi) {
                int row = wr * 32 + mi * 16 + (lane & 15);
                af[mi] = *(const bf16x8*)(Ab + row * 128 + (kb ^ ((row & 7) << 4)));
            }
#pragma unroll
            for (int mi = 0; mi < 2; ++mi)
#pragma unroll
                for (int ni = 0; ni < 4; ++ni)
                    acc[mi][ni] = __builtin_amdgcn_mfma_f32_16x16x32_bf16(af[mi], bw[ni], acc[mi][ni], 0, 0, 0);
        }
        __builtin_amdgcn_s_setprio(0);

        if (kt == 15) {   // fold this n-chunk: gelu + proj partial, reset acc
#pragma unroll
            for (int mi = 0; mi < 2; ++mi)
#pragma unroll
                for (int r = 0; r < 4; ++r) {
                    float sacc = 0.f;
#pragma unroll
                    for (int ni = 0; ni < 4; ++ni) {
                        float z = acc[mi][ni][r] + db[ni];
                        float gl = 0.5f * z * (1.0f + erff(z * 0.70710678118f));
                        sacc += gl * pw[ni];
                    }
                    p[mi][r] += sacc;
#pragma unroll
                    for (int ni = 0; ni < 4; ++ni) acc[mi][ni][r] = 0.f;
                }
        }
    }

    // ---- Reduce p over 16 n-lanes, then over the 4 n-waves via LDS ----
#pragma unroll
    for (int mi = 0; mi < 2; ++mi)
#pragma unroll
        for (int r = 0; r < 4; ++r) {
            float v = p[mi][r];
#pragma unroll
            for (int off = 1; off < 16; off <<= 1) v += __shfl_xor(v, off, 64);
            p[mi][r] = v;
        }
    __syncthreads();
    float* scratch = (float*)&As[0][0];   // 4 waves x 64 rows
    if ((lane & 15) == 0) {
#pragma unroll
        for (int mi = 0; mi < 2; ++mi)
#pragma unroll
            for (int r = 0; r < 4; ++r) {
                int lr = wr * 32 + mi * 16 + ((lane >> 4) << 2) + r;
                scratch[wc * 64 + lr] = p[mi][r];
            }
    }
    __syncthreads();
    if (tid < FBM) {
        float v = proj_b[0] + scratch[tid] + scratch[64 + tid] + scratch[128 + tid] + scratch[192 + tid];
        out[r0 + tid] = v;
    }
}

extern "C" void kernel_launch(void* const* d_in, const int* in_sizes, int n_in,
                              void* d_out, int out_size, void* d_ws, size_t ws_size,
                              hipStream_t stream) {
    const float* hidden       = (const float*)d_in[0];
    const float* dense_w      = (const float*)d_in[1];
    const float* dense_b      = (const float*)d_in[2];
    const float* proj_w       = (const float*)d_in[3];
    const float* proj_b       = (const float*)d_in[4];
    const int*   flat_indices = (const int*)d_in[5];
    const int*   segment_ids  = (const int*)d_in[6];
    float* out = (float*)d_out;

    char* ws = (char*)d_ws;
    int* seg_start = (int*)ws;                                   // 16385 ints
    unsigned short* hbf = (unsigned short*)(ws + (1 << 17));     // 32MB
    unsigned short* wbf = (unsigned short*)(ws + (1 << 17) + (size_t)NSEG * H * 2);  // 2MB

    hipLaunchKernelGGL(setup_kernel, dim3(1089), dim3(256), 0, stream,
                       dense_w, wbf, segment_ids, seg_start);
    hipLaunchKernelGGL(fused_kernel, dim3(256), dim3(512), 0, stream,
                       hidden, flat_indices, seg_start, wbf, dense_b, proj_w, proj_b, hbf, out);
}

// Round 5
// 106.145 us; speedup vs baseline: 1.6587x; 1.6587x over previous
//
#include <hip/hip_runtime.h>

#define H 1024
#define NG 65536
#define NSEG 16384

#define BM 256
#define BN 256
#define BK 64
#define NT (H / BK)   // 16 K-tiles

typedef __attribute__((ext_vector_type(8))) short bf16x8;
typedef __attribute__((ext_vector_type(4))) float f32x4;

__device__ __forceinline__ unsigned short f2bf(float x) {
    unsigned u = __builtin_bit_cast(unsigned, x);
    unsigned r = (u + 0x7fffu + ((u >> 16) & 1u)) >> 16;
    return (unsigned short)r;
}

__device__ __forceinline__ void gload_lds16(const void* g, void* l) {
    __builtin_amdgcn_global_load_lds(
        (const __attribute__((address_space(1))) void*)g,
        (__attribute__((address_space(3))) void*)l, 16, 0, 0);
}

#define CFENCE() asm volatile("" ::: "memory")

// ---- Fused setup: convert W to bf16 | init out=proj_b | segment bounds ----
__global__ void setup_kernel(const float* __restrict__ w, unsigned short* __restrict__ wbf,
                             const float* __restrict__ proj_b, float* __restrict__ out,
                             const int* __restrict__ seg, int* __restrict__ seg_start) {
    int b = blockIdx.x;
    if (b < 1024) {
        int i = (b * 256 + threadIdx.x) * 4;
        float4 v = *(const float4*)(w + i);
        ushort4 o;
        o.x = f2bf(v.x); o.y = f2bf(v.y); o.z = f2bf(v.z); o.w = f2bf(v.w);
        *(ushort4*)(wbf + i) = o;
    } else if (b < 1088) {
        int i = (b - 1024) * 256 + threadIdx.x;
        if (i < NSEG) out[i] = proj_b[0];
    } else {
        int g = (b - 1088) * 256 + threadIdx.x;
        if (g > NSEG) return;
        if (g == NSEG) { seg_start[g] = NG; return; }
        int lo = 0, hi = NG;
        while (lo < hi) { int mid = (lo + hi) >> 1; if (seg[mid] < g) lo = mid + 1; else hi = mid; }
        seg_start[g] = lo;
    }
}

// ---- Gather + segment mean: ONE WAVE PER SEGMENT, register-resident indices ----
// Lane L accumulates columns {256c + 4L .. 256c + 4L+3} for c in 0..3 (16 f32).
__global__ void seg_mean_kernel(const float* __restrict__ hidden,
                                const int* __restrict__ flat_indices,
                                const int* __restrict__ seg_start,
                                unsigned short* __restrict__ hbf) {
    int g = (blockIdx.x << 2) + (threadIdx.x >> 6);   // global wave id = segment
    int lane = threadIdx.x & 63;
    int s = seg_start[g], e = seg_start[g + 1];
    int len = e - s;

    float4 acc[4] = {{0.f,0.f,0.f,0.f},{0.f,0.f,0.f,0.f},{0.f,0.f,0.f,0.f},{0.f,0.f,0.f,0.f}};

    for (int base = 0; base < len; base += 64) {
        int nb = len - base; if (nb > 64) nb = 64;
        // One coalesced load covers all indices of this batch; shfl broadcasts.
        int idx = (base + lane < len) ? flat_indices[s + base + lane] : 0;
        int i = 0;
        for (; i + 4 <= nb; i += 4) {
            int r0 = __shfl(idx, i, 64);
            int r1 = __shfl(idx, i + 1, 64);
            int r2 = __shfl(idx, i + 2, 64);
            int r3 = __shfl(idx, i + 3, 64);
            const float4* p0 = (const float4*)(hidden + (size_t)r0 * H) + lane;
            const float4* p1 = (const float4*)(hidden + (size_t)r1 * H) + lane;
            const float4* p2 = (const float4*)(hidden + (size_t)r2 * H) + lane;
            const float4* p3 = (const float4*)(hidden + (size_t)r3 * H) + lane;
            float4 v0[4], v1[4], v2[4], v3[4];
#pragma unroll
            for (int c = 0; c < 4; ++c) { v0[c] = p0[c * 64]; v1[c] = p1[c * 64]; v2[c] = p2[c * 64]; v3[c] = p3[c * 64]; }
#pragma unroll
            for (int c = 0; c < 4; ++c) {
                acc[c].x += v0[c].x + v1[c].x + v2[c].x + v3[c].x;
                acc[c].y += v0[c].y + v1[c].y + v2[c].y + v3[c].y;
                acc[c].z += v0[c].z + v1[c].z + v2[c].z + v3[c].z;
                acc[c].w += v0[c].w + v1[c].w + v2[c].w + v3[c].w;
            }
        }
        for (; i < nb; ++i) {
            int r = __shfl(idx, i, 64);
            const float4* p = (const float4*)(hidden + (size_t)r * H) + lane;
#pragma unroll
            for (int c = 0; c < 4; ++c) {
                float4 v = p[c * 64];
                acc[c].x += v.x; acc[c].y += v.y; acc[c].z += v.z; acc[c].w += v.w;
            }
        }
    }

    float sc = (len > 0) ? 1.0f / (float)len : 0.0f;
#pragma unroll
    for (int c = 0; c < 4; ++c) {
        ushort4 o;
        o.x = f2bf(acc[c].x * sc); o.y = f2bf(acc[c].y * sc);
        o.z = f2bf(acc[c].z * sc); o.w = f2bf(acc[c].w * sc);
        *(ushort4*)(hbf + (size_t)g * H + c * 256 + lane * 4) = o;
    }
}

// ---- 256x256 bf16 MFMA GEMM, double-buffered, counted-vmcnt pipeline ----
__global__ __launch_bounds__(512, 2) void gemm_kernel(
    const unsigned short* __restrict__ Abf,   // h bf16 [NSEG, H]
    const unsigned short* __restrict__ Wbf,   // dense_w bf16 [H, H] (row n contiguous in k)
    const float* __restrict__ dense_b,
    const float* __restrict__ proj_w,
    float* __restrict__ out) {
    __shared__ unsigned short As[2][BM * BK];  // 2 x 32 KB
    __shared__ unsigned short Bs[2][BN * BK];  // 2 x 32 KB
    const int tid = threadIdx.x;
    const int wid = tid >> 6, lane = tid & 63;
    const int wr = wid >> 2, wc = wid & 3;         // wave tile: 128 rows x 64 cols
    const int m0 = blockIdx.x * BM, n0 = blockIdx.y * BN;

    f32x4 acc[8][4] = {};

    auto STAGE = [&](int buf, int kt) {
#pragma unroll
        for (int it = 0; it < 4; ++it) {
            int c = it * 512 + tid;                 // 16B chunk index, 0..2047
            int row = c >> 3;
            int sw = ((c & 7) << 4) ^ ((row & 7) << 4);
            gload_lds16((const char*)Abf + (((size_t)(m0 + row)) << 11) + kt * 128 + sw,
                        (char*)&As[buf][0] + (it * 512 + wid * 64) * 16);
        }
#pragma unroll
        for (int it = 0; it < 4; ++it) {
            int c = it * 512 + tid;
            int row = c >> 3;
            int sw = ((c & 7) << 4) ^ ((row & 7) << 4);
            gload_lds16((const char*)Wbf + (((size_t)(n0 + row)) << 11) + kt * 128 + sw,
                        (char*)&Bs[buf][0] + (it * 512 + wid * 64) * 16);
        }
    };

    STAGE(0, 0);

    for (int t = 0; t < NT; ++t) {
        CFENCE();
        __builtin_amdgcn_s_barrier();
        CFENCE();
        if (t + 1 < NT) {
            STAGE((t + 1) & 1, t + 1);
            asm volatile("s_waitcnt vmcnt(8)" ::: "memory");
        } else {
            asm volatile("s_waitcnt vmcnt(0)" ::: "memory");
        }
        __builtin_amdgcn_s_barrier();
        CFENCE();

        const char* Ab = (const char*)&As[t & 1][0];
        const char* Bb = (const char*)&Bs[t & 1][0];
        __builtin_amdgcn_s_setprio(1);
#pragma unroll
        for (int kk = 0; kk < 2; ++kk) {
            bf16x8 af[8], bw[4];
            int kb = kk * 64 + ((lane >> 4) << 4);
#pragma unroll
            for (int ni = 0; ni < 4; ++ni) {
                int row = wc * 64 + ni * 16 + (lane & 15);
                bw[ni] = *(const bf16x8*)(Bb + row * 128 + (kb ^ ((row & 7) << 4)));
            }
#pragma unroll
            for (int mi = 0; mi < 8; ++mi) {
                int row = wr * 128 + mi * 16 + (lane & 15);
                af[mi] = *(const bf16x8*)(Ab + row * 128 + (kb ^ ((row & 7) << 4)));
            }
#pragma unroll
            for (int mi = 0; mi < 8; ++mi)
#pragma unroll
                for (int ni = 0; ni < 4; ++ni)
                    acc[mi][ni] = __builtin_amdgcn_mfma_f32_16x16x32_bf16(af[mi], bw[ni], acc[mi][ni], 0, 0, 0);
        }
        __builtin_amdgcn_s_setprio(0);
    }

    float db[4], pw[4];
#pragma unroll
    for (int ni = 0; ni < 4; ++ni) {
        int n = n0 + wc * 64 + ni * 16 + (lane & 15);
        db[ni] = dense_b[n];
        pw[ni] = proj_w[n];
    }
#pragma unroll
    for (int mi = 0; mi < 8; ++mi) {
#pragma unroll
        for (int r = 0; r < 4; ++r) {
            int m = m0 + wr * 128 + mi * 16 + ((lane >> 4) << 2) + r;
            float s = 0.f;
#pragma unroll
            for (int ni = 0; ni < 4; ++ni) {
                float z = acc[mi][ni][r] + db[ni];
                float gl = 0.5f * z * (1.0f + erff(z * 0.70710678118f));
                s += gl * pw[ni];
            }
#pragma unroll
            for (int off = 1; off < 16; off <<= 1) s += __shfl_xor(s, off, 64);
            if ((lane & 15) == 0) atomicAdd(out + m, s);
        }
    }
}

extern "C" void kernel_launch(void* const* d_in, const int* in_sizes, int n_in,
                              void* d_out, int out_size, void* d_ws, size_t ws_size,
                              hipStream_t stream) {
    const float* hidden       = (const float*)d_in[0];
    const float* dense_w      = (const float*)d_in[1];
    const float* dense_b      = (const float*)d_in[2];
    const float* proj_w       = (const float*)d_in[3];
    const float* proj_b       = (const float*)d_in[4];
    const int*   flat_indices = (const int*)d_in[5];
    const int*   segment_ids  = (const int*)d_in[6];
    float* out = (float*)d_out;

    char* ws = (char*)d_ws;
    int* seg_start = (int*)ws;                                   // 16385 ints
    unsigned short* hbf = (unsigned short*)(ws + (1 << 17));     // 32MB
    unsigned short* wbf = (unsigned short*)(ws + (1 << 17) + (size_t)NSEG * H * 2);  // 2MB

    hipLaunchKernelGGL(setup_kernel, dim3(1153), dim3(256), 0, stream,
                       dense_w, wbf, proj_b, out, segment_ids, seg_start);
    hipLaunchKernelGGL(seg_mean_kernel, dim3(NSEG / 4), dim3(256), 0, stream,
                       hidden, flat_indices, seg_start, hbf);
    hipLaunchKernelGGL(gemm_kernel, dim3(NSEG / BM, H / BN), dim3(512), 0, stream,
                       hbf, wbf, dense_b, proj_w, out);
}

// Round 6
// 103.528 us; speedup vs baseline: 1.7006x; 1.0253x over previous
//
#include <hip/hip_runtime.h>

#define H 1024
#define NG 65536
#define NSEG 16384

#define BM 256
#define BN 256
#define BK 64
#define NT (H / BK)   // 16 K-tiles

typedef __attribute__((ext_vector_type(8))) short bf16x8;
typedef __attribute__((ext_vector_type(4))) float f32x4;

__device__ __forceinline__ unsigned short f2bf(float x) {
    unsigned u = __builtin_bit_cast(unsigned, x);
    unsigned r = (u + 0x7fffu + ((u >> 16) & 1u)) >> 16;
    return (unsigned short)r;
}

__device__ __forceinline__ void gload_lds16(const void* g, void* l) {
    __builtin_amdgcn_global_load_lds(
        (const __attribute__((address_space(1))) void*)g,
        (__attribute__((address_space(3))) void*)l, 16, 0, 0);
}

#define CFENCE() asm volatile("" ::: "memory")

// ---- Fused setup: convert W to bf16 | init out=proj_b | segment bounds ----
__global__ void setup_kernel(const float* __restrict__ w, unsigned short* __restrict__ wbf,
                             const float* __restrict__ proj_b, float* __restrict__ out,
                             const int* __restrict__ seg, int* __restrict__ seg_start) {
    int b = blockIdx.x;
    if (b < 1024) {
        int i = (b * 256 + threadIdx.x) * 4;
        float4 v = *(const float4*)(w + i);
        ushort4 o;
        o.x = f2bf(v.x); o.y = f2bf(v.y); o.z = f2bf(v.z); o.w = f2bf(v.w);
        *(ushort4*)(wbf + i) = o;
    } else if (b < 1088) {
        int i = (b - 1024) * 256 + threadIdx.x;
        if (i < NSEG) out[i] = proj_b[0];
    } else {
        int g = (b - 1088) * 256 + threadIdx.x;
        if (g > NSEG) return;
        if (g == NSEG) { seg_start[g] = NG; return; }
        int lo = 0, hi = NG;
        while (lo < hi) { int mid = (lo + hi) >> 1; if (seg[mid] < g) lo = mid + 1; else hi = mid; }
        seg_start[g] = lo;
    }
}

// ---- Gather + segment mean -> bf16 h [NSEG, H] (block-per-segment, best known) ----
__global__ void seg_mean_kernel(const float* __restrict__ hidden,
                                const int* __restrict__ flat_indices,
                                const int* __restrict__ seg_start,
                                unsigned short* __restrict__ hbf) {
    int g = blockIdx.x;
    int t = threadIdx.x;  // 256 threads, 4 floats each
    int s = seg_start[g], e = seg_start[g + 1];
    float4 acc = {0.f, 0.f, 0.f, 0.f};
    for (int i = s; i < e; ++i) {
        int row = flat_indices[i];
        float4 v = *((const float4*)(hidden + (size_t)row * H) + t);
        acc.x += v.x; acc.y += v.y; acc.z += v.z; acc.w += v.w;
    }
    float scale = (e > s) ? 1.0f / (float)(e - s) : 0.0f;
    ushort4 o;
    o.x = f2bf(acc.x * scale); o.y = f2bf(acc.y * scale);
    o.z = f2bf(acc.z * scale); o.w = f2bf(acc.w * scale);
    *(ushort4*)(hbf + (size_t)g * H + t * 4) = o;
}

// ---- 256x256 bf16 MFMA GEMM, double-buffered, counted-vmcnt pipeline ----
__global__ __launch_bounds__(512, 2) void gemm_kernel(
    const unsigned short* __restrict__ Abf,   // h bf16 [NSEG, H]
    const unsigned short* __restrict__ Wbf,   // dense_w bf16 [H, H] (row n contiguous in k)
    const float* __restrict__ dense_b,
    const float* __restrict__ proj_w,
    float* __restrict__ out) {
    __shared__ unsigned short As[2][BM * BK];  // 2 x 32 KB
    __shared__ unsigned short Bs[2][BN * BK];  // 2 x 32 KB
    const int tid = threadIdx.x;
    const int wid = tid >> 6, lane = tid & 63;
    const int wr = wid >> 2, wc = wid & 3;         // wave tile: 128 rows x 64 cols
    const int m0 = blockIdx.x * BM, n0 = blockIdx.y * BN;

    f32x4 acc[8][4] = {};

    auto STAGE = [&](int buf, int kt) {
#pragma unroll
        for (int it = 0; it < 4; ++it) {
            int c = it * 512 + tid;                 // 16B chunk index, 0..2047
            int row = c >> 3;
            int sw = ((c & 7) << 4) ^ ((row & 7) << 4);
            gload_lds16((const char*)Abf + (((size_t)(m0 + row)) << 11) + kt * 128 + sw,
                        (char*)&As[buf][0] + (it * 512 + wid * 64) * 16);
        }
#pragma unroll
        for (int it = 0; it < 4; ++it) {
            int c = it * 512 + tid;
            int row = c >> 3;
            int sw = ((c & 7) << 4) ^ ((row & 7) << 4);
            gload_lds16((const char*)Wbf + (((size_t)(n0 + row)) << 11) + kt * 128 + sw,
                        (char*)&Bs[buf][0] + (it * 512 + wid * 64) * 16);
        }
    };

    STAGE(0, 0);

    for (int t = 0; t < NT; ++t) {
        CFENCE();
        __builtin_amdgcn_s_barrier();
        CFENCE();
        if (t + 1 < NT) {
            STAGE((t + 1) & 1, t + 1);
            asm volatile("s_waitcnt vmcnt(8)" ::: "memory");
        } else {
            asm volatile("s_waitcnt vmcnt(0)" ::: "memory");
        }
        __builtin_amdgcn_s_barrier();
        CFENCE();

        const char* Ab = (const char*)&As[t & 1][0];
        const char* Bb = (const char*)&Bs[t & 1][0];
        __builtin_amdgcn_s_setprio(1);
#pragma unroll
        for (int kk = 0; kk < 2; ++kk) {
            bf16x8 af[8], bw[4];
            int kb = kk * 64 + ((lane >> 4) << 4);
#pragma unroll
            for (int ni = 0; ni < 4; ++ni) {
                int row = wc * 64 + ni * 16 + (lane & 15);
                bw[ni] = *(const bf16x8*)(Bb + row * 128 + (kb ^ ((row & 7) << 4)));
            }
#pragma unroll
            for (int mi = 0; mi < 8; ++mi) {
                int row = wr * 128 + mi * 16 + (lane & 15);
                af[mi] = *(const bf16x8*)(Ab + row * 128 + (kb ^ ((row & 7) << 4)));
            }
#pragma unroll
            for (int mi = 0; mi < 8; ++mi)
#pragma unroll
                for (int ni = 0; ni < 4; ++ni)
                    acc[mi][ni] = __builtin_amdgcn_mfma_f32_16x16x32_bf16(af[mi], bw[ni], acc[mi][ni], 0, 0, 0);
        }
        __builtin_amdgcn_s_setprio(0);
    }

    float db[4], pw[4];
#pragma unroll
    for (int ni = 0; ni < 4; ++ni) {
        int n = n0 + wc * 64 + ni * 16 + (lane & 15);
        db[ni] = dense_b[n];
        pw[ni] = proj_w[n];
    }
#pragma unroll
    for (int mi = 0; mi < 8; ++mi) {
#pragma unroll
        for (int r = 0; r < 4; ++r) {
            int m = m0 + wr * 128 + mi * 16 + ((lane >> 4) << 2) + r;
            float s = 0.f;
#pragma unroll
            for (int ni = 0; ni < 4; ++ni) {
                float z = acc[mi][ni][r] + db[ni];
                float gl = 0.5f * z * (1.0f + erff(z * 0.70710678118f));
                s += gl * pw[ni];
            }
#pragma unroll
            for (int off = 1; off < 16; off <<= 1) s += __shfl_xor(s, off, 64);
            if ((lane & 15) == 0) atomicAdd(out + m, s);
        }
    }
}

extern "C" void kernel_launch(void* const* d_in, const int* in_sizes, int n_in,
                              void* d_out, int out_size, void* d_ws, size_t ws_size,
                              hipStream_t stream) {
    const float* hidden       = (const float*)d_in[0];
    const float* dense_w      = (const float*)d_in[1];
    const float* dense_b      = (const float*)d_in[2];
    const float* proj_w       = (const float*)d_in[3];
    const float* proj_b       = (const float*)d_in[4];
    const int*   flat_indices = (const int*)d_in[5];
    const int*   segment_ids  = (const int*)d_in[6];
    float* out = (float*)d_out;

    char* ws = (char*)d_ws;
    int* seg_start = (int*)ws;                                   // 16385 ints
    unsigned short* hbf = (unsigned short*)(ws + (1 << 17));     // 32MB
    unsigned short* wbf = (unsigned short*)(ws + (1 << 17) + (size_t)NSEG * H * 2);  // 2MB

    hipLaunchKernelGGL(setup_kernel, dim3(1153), dim3(256), 0, stream,
                       dense_w, wbf, proj_b, out, segment_ids, seg_start);
    hipLaunchKernelGGL(seg_mean_kernel, dim3(NSEG), dim3(256), 0, stream,
                       hidden, flat_indices, seg_start, hbf);
    hipLaunchKernelGGL(gemm_kernel, dim3(NSEG / BM, H / BN), dim3(512), 0, stream,
                       hbf, wbf, dense_b, proj_w, out);
}